// Round 1
// baseline (329.294 us; speedup 1.0000x reference)
//
#include <hip/hip_runtime.h>
#include <cstdint>

// ===================== GCN encoder on MI355X =====================
// out = gcn(relu(gcn(x, W1, b1)), W2, b2)
// gcn(x,W,b)[i] = dinv[i] * ( sum_{e: dst=i} (xW*dinv)[src] + (xW*dinv)[i] ) + b
// dinv = rsqrt(indeg+1) (self-loop), identical for both layers.
//
// R7: aggregate gather-locality. bcsr now counting-sorts each bucket by
// (local_dst, src_octant) key = packed>>14 (1024 LDS counters), so each
// node's edge list is in ascending-src order. Co-resident aggregate waves
// then touch ~2 octants (~3.2 MB) of the 12.8 MB message table at a time,
// fitting the 4 MiB per-XCD L2 (previously ~70% of random 128B gathers
// missed to LLC at ~5 TB/s). aggregate also uses nontemporal loads (csr)
// and stores (output) to keep the streams from evicting the table.
// R6 build pipeline + MFMA GEMMs otherwise unchanged.

#define BSHIFT 7          // 128 nodes per bucket
#define NBMAX 784         // >= ceil(100000/128) = 782
#define CH 4096           // edges per block in passes A/C
#define MAXB 6016         // LDS-cached bucket capacity (avg 4096, +30 sigma)

typedef __attribute__((ext_vector_type(8))) short bf16x8;
typedef __attribute__((ext_vector_type(4))) float f32x4;
typedef __attribute__((ext_vector_type(4))) unsigned int u32x4;

// ---------------- bf16 helpers ----------------
__device__ inline unsigned short f2bf(float f) {
    unsigned u = __float_as_uint(f);
    unsigned r = (u + 0x7FFFu + ((u >> 16) & 1u)) >> 16;  // RNE
    return (unsigned short)r;
}
__device__ inline unsigned pack2(float a, float b) {
    return (unsigned)f2bf(a) | ((unsigned)f2bf(b) << 16);
}
__device__ inline float blo(unsigned u) { return __uint_as_float(u << 16); }
__device__ inline float bhi(unsigned u) { return __uint_as_float(u & 0xFFFF0000u); }

// ---------------- pass A: bucket histogram (+ folded weight prep) ----------
__global__ __launch_bounds__(256) void hist_kernel(const int* __restrict__ dst,
                                                   int* __restrict__ histmat,
                                                   int E, int nb, int nblk,
                                                   const float* __restrict__ W1,
                                                   const float* __restrict__ W2,
                                                   unsigned short* __restrict__ W1t,
                                                   unsigned short* __restrict__ W2t) {
    if (blockIdx.x >= (unsigned)nblk) {
        // weight-prep blocks: W[K][64] fp32 -> Wt[64][K] bf16
        int i = (blockIdx.x - nblk) * 256 + threadIdx.x;
        if (i < 128 * 64) {
            int k = i >> 6, n = i & 63;
            W1t[n * 128 + k] = f2bf(W1[i]);
        }
        int j = i - 128 * 64;
        if (j >= 0 && j < 64 * 64) {
            int k = j >> 6, n = j & 63;
            W2t[n * 64 + k] = f2bf(W2[j]);
        }
        return;
    }
    __shared__ int hist[NBMAX];
    int t = threadIdx.x;
    for (int b = t; b < nb; b += 256) hist[b] = 0;
    __syncthreads();
    int base = blockIdx.x * CH;
#pragma unroll
    for (int j = 0; j < CH / 1024; ++j) {
        int idx = base + j * 1024 + t * 4;
        if (idx + 4 <= E) {
            int4 d = *(const int4*)(dst + idx);
            atomicAdd(&hist[d.x >> BSHIFT], 1);
            atomicAdd(&hist[d.y >> BSHIFT], 1);
            atomicAdd(&hist[d.z >> BSHIFT], 1);
            atomicAdd(&hist[d.w >> BSHIFT], 1);
        } else {
            for (int k = 0; k < 4; ++k)
                if (idx + k < E) atomicAdd(&hist[dst[idx + k] >> BSHIFT], 1);
        }
    }
    __syncthreads();
    for (int b = t; b < nb; b += 256) histmat[blockIdx.x * nb + b] = hist[b];
}

// ---------------- pass B1: per-bucket scan over blocks (nblk <= 1024) -------
__global__ __launch_bounds__(256) void scancol_kernel(const int* __restrict__ histmat,
                                                      int* __restrict__ colbase,
                                                      int* __restrict__ buckettotal,
                                                      int nb, int nblk) {
    __shared__ int ts[256];
    int b = blockIdx.x;
    int t = threadIdx.x;
    int v[4];
    int tsum = 0;
#pragma unroll
    for (int k = 0; k < 4; ++k) {
        int blk = t * 4 + k;
        v[k] = (blk < nblk) ? histmat[blk * nb + b] : 0;
        tsum += v[k];
    }
    ts[t] = tsum;
    __syncthreads();
    for (int ofs = 1; ofs < 256; ofs <<= 1) {
        int val = (t >= ofs) ? ts[t - ofs] : 0;
        __syncthreads();
        ts[t] += val;
        __syncthreads();
    }
    int run = ts[t] - tsum;
#pragma unroll
    for (int k = 0; k < 4; ++k) {
        int blk = t * 4 + k;
        if (blk < nblk) colbase[blk * nb + b] = run;
        run += v[k];
    }
    if (t == 255) buckettotal[b] = ts[255];
}

// ---------------- pass B2: scan bucket totals (single block) ----------------
__global__ __launch_bounds__(256) void scanbucket_kernel(const int* __restrict__ buckettotal,
                                                         int* __restrict__ bucketbase,
                                                         int nb, int E) {
    __shared__ int ts[256];
    int t = threadIdx.x;
    int v[4];
    int tsum = 0;
#pragma unroll
    for (int k = 0; k < 4; ++k) {
        int b = t * 4 + k;
        v[k] = (b < nb) ? buckettotal[b] : 0;
        tsum += v[k];
    }
    ts[t] = tsum;
    __syncthreads();
    for (int ofs = 1; ofs < 256; ofs <<= 1) {
        int val = (t >= ofs) ? ts[t - ofs] : 0;
        __syncthreads();
        ts[t] += val;
        __syncthreads();
    }
    int run = ts[t] - tsum;
#pragma unroll
    for (int k = 0; k < 4; ++k) {
        int b = t * 4 + k;
        if (b < nb) bucketbase[b] = run;
        run += v[k];
    }
    if (t == 0) bucketbase[nb] = E;
}

// ---------------- pass C: scatter into bucket regions (LDS cursors) ---------
__global__ __launch_bounds__(256) void bscatter_kernel(const int* __restrict__ src,
                                                       const int* __restrict__ dst,
                                                       const int* __restrict__ colbase,
                                                       const int* __restrict__ bucketbase,
                                                       int* __restrict__ packed,
                                                       int E, int nb) {
    __shared__ int cur[NBMAX];
    int t = threadIdx.x;
    for (int b = t; b < nb; b += 256)
        cur[b] = bucketbase[b] + colbase[blockIdx.x * nb + b];
    __syncthreads();
    int base = blockIdx.x * CH;
#pragma unroll
    for (int j = 0; j < CH / 1024; ++j) {
        int idx = base + j * 1024 + t * 4;
        if (idx + 4 <= E) {
            int4 d = *(const int4*)(dst + idx);
            int4 s = *(const int4*)(src + idx);
            int p;
            p = atomicAdd(&cur[d.x >> BSHIFT], 1); packed[p] = ((d.x & 127) << 17) | s.x;
            p = atomicAdd(&cur[d.y >> BSHIFT], 1); packed[p] = ((d.y & 127) << 17) | s.y;
            p = atomicAdd(&cur[d.z >> BSHIFT], 1); packed[p] = ((d.z & 127) << 17) | s.z;
            p = atomicAdd(&cur[d.w >> BSHIFT], 1); packed[p] = ((d.w & 127) << 17) | s.w;
        } else {
            for (int k = 0; k < 4; ++k)
                if (idx + k < E) {
                    int dd = dst[idx + k], ss = src[idx + k];
                    int p = atomicAdd(&cur[dd >> BSHIFT], 1);
                    packed[p] = ((dd & 127) << 17) | ss;
                }
        }
    }
}

// ------- pass D: within-bucket (node, src-octant) sort + rowptr + dinv ------
// key = packed >> 14 : [local_dst(7b) | src bits 16:14 (3b)] -> 1024 keys.
// Sorting by key orders each node's edges by ascending src octant, giving
// the aggregate pass temporal locality in its random gathers.
__global__ __launch_bounds__(256) void bcsr_kernel(const int* __restrict__ packed,
                                                   const int* __restrict__ bucketbase,
                                                   int* __restrict__ rowptr,
                                                   float* __restrict__ dinv,
                                                   int* __restrict__ csr,
                                                   int N, int nb) {
    __shared__ int cnt[1025];   // per-key counts -> exclusive starts -> cursors
    __shared__ int ts[256];
    __shared__ int ebuf[MAXB];
    __shared__ int obuf[MAXB];
    int b = blockIdx.x;
    int t = threadIdx.x;
    for (int i = t; i < 1024; i += 256) cnt[i] = 0;
    __syncthreads();
    int bb0 = bucketbase[b];
    int bb1 = bucketbase[b + 1];
    int cnt_e = bb1 - bb0;
    bool fits = (cnt_e <= MAXB);
    if (fits) {
        for (int i = t; i < cnt_e; i += 256) {
            int v = packed[bb0 + i];
            ebuf[i] = v;
            atomicAdd(&cnt[v >> 14], 1);
        }
    } else {
        for (int i = t; i < cnt_e; i += 256)
            atomicAdd(&cnt[packed[bb0 + i] >> 14], 1);
    }
    __syncthreads();
    // exclusive scan of 1024 counts (4 per thread + block scan)
    int v4[4];
    int tsum = 0;
#pragma unroll
    for (int k = 0; k < 4; ++k) {
        v4[k] = cnt[t * 4 + k];
        tsum += v4[k];
    }
    ts[t] = tsum;
    __syncthreads();
    for (int ofs = 1; ofs < 256; ofs <<= 1) {
        int val = (t >= ofs) ? ts[t - ofs] : 0;
        __syncthreads();
        ts[t] += val;
        __syncthreads();
    }
    int run = ts[t] - tsum;
#pragma unroll
    for (int k = 0; k < 4; ++k) {
        int c = v4[k];
        cnt[t * 4 + k] = run;   // exclusive start for this key
        run += c;
    }
    if (t == 255) cnt[1024] = run;  // == cnt_e
    __syncthreads();
    int node0 = b << BSHIFT;
    int nlocal = min(128, N - node0);
    if (t < nlocal) {
        int s0 = cnt[t * 8];
        int deg = cnt[(t + 1) * 8] - s0;
        rowptr[node0 + t] = bb0 + s0;
        dinv[node0 + t] = rsqrtf((float)(deg + 1));
    }
    if (t == nlocal) rowptr[node0 + nlocal] = bb1;
    __syncthreads();   // rowptr/deg reads done before cursors mutate
    if (fits) {
        for (int i = t; i < cnt_e; i += 256) {
            int v = ebuf[i];
            int p = atomicAdd(&cnt[v >> 14], 1);
            obuf[p] = v & 0x1FFFF;
        }
        __syncthreads();
        for (int i = t; i < cnt_e; i += 256) csr[bb0 + i] = obuf[i];  // coalesced
    } else {
        for (int i = t; i < cnt_e; i += 256) {
            int v = packed[bb0 + i];
            int p = atomicAdd(&cnt[v >> 14], 1);
            csr[bb0 + p] = v & 0x1FFFF;
        }
    }
}

// ------- MFMA GEMM: Ybf[M,64](bf16) = (X[M,K] @ W[K,64]) * dinv[row] -------
template <int K, bool XBF16>
__global__ __launch_bounds__(256) void gemm_mfma(const void* __restrict__ Xv,
                                                 const unsigned short* __restrict__ Wt,
                                                 const float* __restrict__ dinv,
                                                 unsigned short* __restrict__ Ybf, int M) {
    constexpr int KP = K + 8;
    __shared__ unsigned short Xs[64 * KP];   // reused as Cs (64*72) in epilogue
    __shared__ unsigned short Ws[64 * KP];
    int t = threadIdx.x;
    int row0 = blockIdx.x * 64;

    for (int i = t; i < 64 * K / 8; i += 256) {
        int r = i / (K / 8), c8 = i % (K / 8);
        *(uint4*)(&Ws[r * KP + c8 * 8]) = ((const uint4*)Wt)[i];
    }
    if (XBF16) {
        const unsigned short* X = (const unsigned short*)Xv;
        for (int i = t; i < 64 * K / 8; i += 256) {
            int r = i / (K / 8), c8 = i % (K / 8);
            int gr = row0 + r;
            uint4 v = make_uint4(0u, 0u, 0u, 0u);
            if (gr < M) v = ((const uint4*)(X + (size_t)gr * K))[c8];
            *(uint4*)(&Xs[r * KP + c8 * 8]) = v;
        }
    } else {
        const float* X = (const float*)Xv;
        for (int i = t; i < 64 * K / 4; i += 256) {
            int r = i / (K / 4), c4 = i % (K / 4);
            int gr = row0 + r;
            float4 v = make_float4(0.f, 0.f, 0.f, 0.f);
            if (gr < M) v = ((const float4*)(X + (size_t)gr * K))[c4];
            uint2 p;
            p.x = pack2(v.x, v.y);
            p.y = pack2(v.z, v.w);
            *(uint2*)(&Xs[r * KP + c4 * 4]) = p;
        }
    }
    __syncthreads();

    int lane = t & 63;
    int w = t >> 6;
    int m = lane & 15;
    int q = lane >> 4;

    f32x4 acc[4];
#pragma unroll
    for (int nt = 0; nt < 4; ++nt) acc[nt] = (f32x4){0.f, 0.f, 0.f, 0.f};

#pragma unroll
    for (int s = 0; s < K / 32; ++s) {
        bf16x8 a = *(const bf16x8*)(&Xs[(16 * w + m) * KP + s * 32 + q * 8]);
#pragma unroll
        for (int nt = 0; nt < 4; ++nt) {
            bf16x8 b = *(const bf16x8*)(&Ws[(16 * nt + m) * KP + s * 32 + q * 8]);
            acc[nt] = __builtin_amdgcn_mfma_f32_16x16x32_bf16(a, b, acc[nt], 0, 0, 0);
        }
    }
    __syncthreads();

    unsigned short* Cs = Xs;
#pragma unroll
    for (int nt = 0; nt < 4; ++nt)
#pragma unroll
        for (int r = 0; r < 4; ++r) {
            int row = 16 * w + q * 4 + r;
            int gr = row0 + row;
            float d = (gr < M) ? dinv[gr] : 0.f;
            Cs[row * 72 + nt * 16 + m] = f2bf(acc[nt][r] * d);
        }
    __syncthreads();
    for (int i = t; i < 64 * 64 / 8; i += 256) {
        int r = i >> 3, c8 = i & 7;
        int gr = row0 + r;
        if (gr < M)
            *(uint4*)(Ybf + (size_t)gr * 64 + c8 * 8) = *(const uint4*)(&Cs[r * 72 + c8 * 8]);
    }
}

// ---------------- pull aggregation + epilogue ----------------
__global__ __launch_bounds__(256) void aggregate_kernel(const unsigned* __restrict__ hsu,
                                                        const int* __restrict__ rowptr,
                                                        const int* __restrict__ csr,
                                                        const float* __restrict__ dinv,
                                                        const float* __restrict__ bias,
                                                        void* __restrict__ outv, int N,
                                                        int do_relu, int obf) {
    int t = threadIdx.x;
    int node = blockIdx.x * 32 + (t >> 3);
    if (node >= N) return;
    int sub = t & 7;
    int gbase = t & 56;

    float acc[8];
    {
        uint4 v = *(const uint4*)(hsu + (size_t)node * 32 + sub * 4);  // self-loop
        acc[0] = blo(v.x); acc[1] = bhi(v.x);
        acc[2] = blo(v.y); acc[3] = bhi(v.y);
        acc[4] = blo(v.z); acc[5] = bhi(v.z);
        acc[6] = blo(v.w); acc[7] = bhi(v.w);
    }
    int e0 = rowptr[node];
    int e1 = rowptr[node + 1];

    int e = e0;
    for (; e + 8 <= e1; e += 8) {
        int idx = __builtin_nontemporal_load(csr + e + sub);  // streaming: keep table in L2
#pragma unroll
        for (int j = 0; j < 8; ++j) {
            int s = __shfl(idx, gbase + j, 64);
            uint4 v = *(const uint4*)(hsu + (size_t)s * 32 + sub * 4);
            acc[0] += blo(v.x); acc[1] += bhi(v.x);
            acc[2] += blo(v.y); acc[3] += bhi(v.y);
            acc[4] += blo(v.z); acc[5] += bhi(v.z);
            acc[6] += blo(v.w); acc[7] += bhi(v.w);
        }
    }
    for (; e < e1; ++e) {
        int s = __builtin_nontemporal_load(csr + e);
        uint4 v = *(const uint4*)(hsu + (size_t)s * 32 + sub * 4);
        acc[0] += blo(v.x); acc[1] += bhi(v.x);
        acc[2] += blo(v.y); acc[3] += bhi(v.y);
        acc[4] += blo(v.z); acc[5] += bhi(v.z);
        acc[6] += blo(v.w); acc[7] += bhi(v.w);
    }

    float d = dinv[node];
    float4 b0 = *(const float4*)(bias + sub * 8);
    float4 b1 = *(const float4*)(bias + sub * 8 + 4);
    float o[8];
    o[0] = fmaf(acc[0], d, b0.x); o[1] = fmaf(acc[1], d, b0.y);
    o[2] = fmaf(acc[2], d, b0.z); o[3] = fmaf(acc[3], d, b0.w);
    o[4] = fmaf(acc[4], d, b1.x); o[5] = fmaf(acc[5], d, b1.y);
    o[6] = fmaf(acc[6], d, b1.z); o[7] = fmaf(acc[7], d, b1.w);
    if (do_relu) {
#pragma unroll
        for (int k = 0; k < 8; ++k) o[k] = fmaxf(o[k], 0.f);
    }
    if (obf) {
        unsigned short* outb = (unsigned short*)outv;
        u32x4 p;
        p.x = pack2(o[0], o[1]); p.y = pack2(o[2], o[3]);
        p.z = pack2(o[4], o[5]); p.w = pack2(o[6], o[7]);
        __builtin_nontemporal_store(p, (u32x4*)(outb + (size_t)node * 64 + sub * 8));
    } else {
        float* op = (float*)outv + (size_t)node * 64 + sub * 8;
        f32x4 o0 = {o[0], o[1], o[2], o[3]};
        f32x4 o1 = {o[4], o[5], o[6], o[7]};
        __builtin_nontemporal_store(o0, (f32x4*)op);
        __builtin_nontemporal_store(o1, (f32x4*)(op + 4));
    }
}

// ---------------- launch ----------------
extern "C" void kernel_launch(void* const* d_in, const int* in_sizes, int n_in,
                              void* d_out, int out_size, void* d_ws, size_t ws_size,
                              hipStream_t stream) {
    const float* x  = (const float*)d_in[0];
    const int*   ei = (const int*)d_in[1];   // [2, E] int32
    const float* W1 = (const float*)d_in[2];
    const float* b1 = (const float*)d_in[3];
    const float* W2 = (const float*)d_in[4];
    const float* b2 = (const float*)d_in[5];

    const int N = in_sizes[0] / 128;  // 100000
    const int E = in_sizes[1] / 2;    // 3200000
    const int* src = ei;
    const int* dst = ei + E;
    float* out = (float*)d_out;

    const int nb   = (N + 127) >> BSHIFT;  // 782
    const int nblk = (E + CH - 1) / CH;    // 782

    char* ws = (char*)d_ws;
    size_t off = 0;
    auto alloc = [&](size_t bytes) -> char* {
        char* p = ws + off;
        off = (off + bytes + 255) & ~(size_t)255;
        return p;
    };
    // persistent
    int*   csr         = (int*)alloc((size_t)E * 4);
    int*   rowptr      = (int*)alloc((size_t)(N + 1) * 4);
    float* dinv        = (float*)alloc((size_t)N * 4);
    int*   bucketbase  = (int*)alloc((size_t)(nb + 1) * 4);
    int*   buckettotal = (int*)alloc((size_t)nb * 4);
    unsigned short* W1t = (unsigned short*)alloc(64 * 128 * 2);
    unsigned short* W2t = (unsigned short*)alloc(64 * 64 * 2);
    unsigned short* bufA = (unsigned short*)alloc((size_t)N * 64 * 2);  // bf16 h*dinv
    unsigned short* bufB = (unsigned short*)alloc((size_t)N * 64 * 2);  // bf16 relu(agg1)
    // transient (dead before gemm1 writes bufA) — alias bufA+bufB region
    // histmat: nblk*nb*4 = 782*782*4 ~ 2.45 MB; packed: E*4 = 12.8 MB
    int* histmat = (int*)bufA;
    int* packed  = (int*)((char*)bufA + ((size_t)nblk * nb * 4 + 255 & ~(size_t)255) + 256);

    hist_kernel<<<nblk + 48, 256, 0, stream>>>(dst, histmat, E, nb, nblk, W1, W2, W1t, W2t);
    scancol_kernel<<<nb, 256, 0, stream>>>(histmat, histmat, buckettotal, nb, nblk);
    scanbucket_kernel<<<1, 256, 0, stream>>>(buckettotal, bucketbase, nb, E);
    bscatter_kernel<<<nblk, 256, 0, stream>>>(src, dst, histmat, bucketbase, packed, E, nb);
    bcsr_kernel<<<nb, 256, 0, stream>>>(packed, bucketbase, rowptr, dinv, csr, N, nb);

    gemm_mfma<128, false><<<(N + 63) / 64, 256, 0, stream>>>(x, W1t, dinv, bufA, N);
    aggregate_kernel<<<(N + 31) / 32, 256, 0, stream>>>((const unsigned*)bufA, rowptr, csr,
                                                        dinv, b1, bufB, N, 1, 1);
    gemm_mfma<64, true><<<(N + 63) / 64, 256, 0, stream>>>(bufB, W2t, dinv, bufA, N);
    aggregate_kernel<<<(N + 31) / 32, 256, 0, stream>>>((const unsigned*)bufA, rowptr, csr,
                                                        dinv, b2, out, N, 0, 0);
}